// Round 5
// baseline (172.392 us; speedup 1.0000x reference)
//
#include <hip/hip_runtime.h>
#include <hip/hip_bf16.h>

typedef __bf16 bf16x8 __attribute__((ext_vector_type(8)));
typedef float floatx4 __attribute__((ext_vector_type(4)));

__device__ __forceinline__ unsigned short f2bf(float f) {
  __bf16 b = (__bf16)f;
  return __builtin_bit_cast(unsigned short, b);
}

// ---------------------------------------------------------------------------
// Kernel 1: decode w1 bits -> bf16 {-1,0,+1} in MFMA-FRAGMENT-TRANSPOSED order:
//   w1t[(kq*256 + row)*8 + k]  holds W[row][kq*8 + k],  kq in [0,104)
// (K padded 784 -> 832 with zeros: kq 98..103 all-zero so the fused K-loop is
// 26 uniform chunks of 32). Fragment rows for one (chunk, quad, wave) are 16
// consecutive rows = 256 contiguous bytes -> direct-to-VGPR loads coalesce.
// ---------------------------------------------------------------------------
__global__ void decode_w1_kernel(const int* __restrict__ w1p,
                                 const int* __restrict__ m1p,
                                 unsigned short* __restrict__ w1t) {
  int t = blockIdx.x * 256 + threadIdx.x;   // [0, 104*256)
  int r = t & 255;                          // row 0..255
  int j = t >> 8;                           // byte group (kq) 0..103
  unsigned short vals[8];
#pragma unroll
  for (int k = 0; k < 8; ++k) vals[k] = 0;
  if (j < 98) {
    unsigned int v = (unsigned int)w1p[r * 98 + j];
    unsigned int m = (unsigned int)m1p[r * 98 + j];
#pragma unroll
    for (int k = 0; k < 8; ++k) {           // MSB-first per byte (matches _unpack)
      unsigned int bit = (v >> (7 - k)) & 1u;
      unsigned int mk  = (m >> (7 - k)) & 1u;
      vals[k] = (unsigned short)(mk ? (bit ? 0x3F80u : 0xBF80u) : 0u);  // +1/-1/0
    }
  }
  uint4 pack;
  pack.x = (unsigned)vals[0] | ((unsigned)vals[1] << 16);
  pack.y = (unsigned)vals[2] | ((unsigned)vals[3] << 16);
  pack.z = (unsigned)vals[4] | ((unsigned)vals[5] << 16);
  pack.w = (unsigned)vals[6] | ((unsigned)vals[7] << 16);
  *reinterpret_cast<uint4*>(w1t + t * 8) = pack;
}

// ---------------------------------------------------------------------------
// Kernel 2: fused  h = relu(a1 * x@W1^T);  out = a2 * (h@W2^T)
// v6: BM=32, 512 thr (8 waves), grid 1024 (4 blocks/CU assigned, 2 resident).
//  - ONE staging burst: Xs[104][32][8] frag-major bf16 (53KB) = the block's
//    entire K range; all 13 float4 loads/thread issued back-to-back (max MLP).
//  - 26 barrier-free chunks: W fragments straight from L2-resident w1t
//    (contiguous 256B per 16-lane group); full unroll lets the scheduler
//    hoist W loads chunks ahead. acc[2][2] -> ~110 live VGPR, no spills.
//  - 3 barriers total (post-stage, post-compute, post-epilogue-decode).
//   A-frag: A[m=l15][k=quad*8+j]; B-frag: B^T[n=l15][k=quad*8+j];
//   C/D: col=l15, row=quad*4+reg  (m89-verified layouts).
// ---------------------------------------------------------------------------
#define BM 32
#define NCHG 26      // chunks of 32 cols (832 = 26*32)
#define HS_LD 264    // 256 + 8 pad: layer-2 Hs reads conflict-free
#define W2_LD 264

// phase-1 LDS (shorts): Xs[104][32][8] = 26624 shorts = 53248 B
// phase-2 overlay:      Hs[32][264] @ 0,  W2s[16][264] @ 8448 (end 12672)
#define OFF_W2 8448

__global__ __launch_bounds__(512, 4) void fused_kernel(
    const float* __restrict__ x,
    const unsigned short* __restrict__ w1t,
    const int* __restrict__ w2p,
    const int* __restrict__ m2p,
    const float* __restrict__ a1p,
    const float* __restrict__ a2p,
    float* __restrict__ out) {
  __shared__ unsigned short smem[26624];   // 53248 B

  const int tid  = threadIdx.x;
  const int wave = tid >> 6;
  const int lane = tid & 63;
  const int l15  = lane & 15;
  const int quad = lane >> 4;
  const int row0 = blockIdx.x * BM;

  // ---- stage X[32][832] -> Xs frag-major, one burst ----
  {
    const int r  = tid >> 4;          // row 0..31
    const int g0 = tid & 15;          // float4 group base
    float4 xv[13];
#pragma unroll
    for (int it = 0; it < 13; ++it) {
      int g = g0 + it * 16;           // 0..207
      int col = g * 4;
      if (col < 784)
        xv[it] = *reinterpret_cast<const float4*>(
            x + (size_t)(row0 + r) * 784 + col);
      else
        xv[it] = (float4){0.f, 0.f, 0.f, 0.f};   // K pad 784..831
    }
#pragma unroll
    for (int it = 0; it < 13; ++it) {
      int g = g0 + it * 16;
      ushort4 b;
      b.x = f2bf(xv[it].x); b.y = f2bf(xv[it].y);
      b.z = f2bf(xv[it].z); b.w = f2bf(xv[it].w);
      // Xs[kq= g>>1][row r][half g&1]: shorts
      *reinterpret_cast<ushort4*>(&smem[(g >> 1) * 256 + r * 8 + (g & 1) * 4]) = b;
    }
  }
  __syncthreads();   // X ready (barrier 1)

  // ---- layer-1 GEMM: 26 barrier-free chunks ----
  floatx4 acc[2][2];
#pragma unroll
  for (int i = 0; i < 2; ++i)
#pragma unroll
    for (int j = 0; j < 2; ++j) acc[i][j] = (floatx4){0.f, 0.f, 0.f, 0.f};

  const unsigned short* wl = w1t + ((size_t)wave * 32 + l15) * 8;

#pragma unroll
  for (int cl = 0; cl < NCHG; ++cl) {
    bf16x8 af[2], bfv[2];
#pragma unroll
    for (int mi = 0; mi < 2; ++mi)
      af[mi] = *reinterpret_cast<const bf16x8*>(
          &smem[(cl * 4 + quad) * 256 + (mi * 16 + l15) * 8]);
#pragma unroll
    for (int nj = 0; nj < 2; ++nj)
      bfv[nj] = *reinterpret_cast<const bf16x8*>(
          wl + (size_t)(cl * 4 + quad) * 2048 + nj * 128);
#pragma unroll
    for (int mi = 0; mi < 2; ++mi)
#pragma unroll
      for (int nj = 0; nj < 2; ++nj)
        acc[mi][nj] = __builtin_amdgcn_mfma_f32_16x16x32_bf16(
            af[mi], bfv[nj], acc[mi][nj], 0, 0, 0);
  }
  __syncthreads();   // all waves done reading Xs before Hs overlay (barrier 2)

  // ---- epilogue layer 1: h = relu(a1*acc) -> Hs bf16 (overlays Xs) ----
  const float a1 = a1p[0];
  const float a2 = a2p[0];
#pragma unroll
  for (int mi = 0; mi < 2; ++mi) {
#pragma unroll
    for (int nj = 0; nj < 2; ++nj) {
      int col   = wave * 32 + nj * 16 + l15;
      int rbase = mi * 16 + quad * 4;
#pragma unroll
      for (int r = 0; r < 4; ++r) {
        float h = fmaxf(a1 * acc[mi][nj][r], 0.f);
        smem[(rbase + r) * HS_LD + col] = f2bf(h);
      }
    }
  }
  // ---- decode w2 -> W2s[16][264] (rows 10..15 zero) ----
  if (tid < 320) {
    int r = tid >> 5, j = tid & 31;
    unsigned int v = (unsigned int)w2p[r * 32 + j];
    unsigned int m = (unsigned int)m2p[r * 32 + j];
#pragma unroll
    for (int k = 0; k < 8; ++k) {
      unsigned int bit = (v >> (7 - k)) & 1u;
      unsigned int mk  = (m >> (7 - k)) & 1u;
      smem[OFF_W2 + r * W2_LD + j * 8 + k] =
          (unsigned short)(mk ? (bit ? 0x3F80u : 0xBF80u) : 0u);
    }
  }
  for (int idx = tid; idx < 6 * 256; idx += 512) {
    int r = 10 + (idx >> 8), c = idx & 255;
    smem[OFF_W2 + r * W2_LD + c] = 0;
  }
  __syncthreads();   // barrier 3

  // ---- layer 2: out[32][10] = Hs @ W2s^T; waves 0..1, 16 rows each, K=256 ----
  if (wave < 2) {
    floatx4 o2 = (floatx4){0.f, 0.f, 0.f, 0.f};
#pragma unroll
    for (int ks = 0; ks < 8; ++ks) {
      bf16x8 ha = *reinterpret_cast<const bf16x8*>(
          &smem[(wave * 16 + l15) * HS_LD + ks * 32 + quad * 8]);
      bf16x8 wb = *reinterpret_cast<const bf16x8*>(
          &smem[OFF_W2 + l15 * W2_LD + ks * 32 + quad * 8]);
      o2 = __builtin_amdgcn_mfma_f32_16x16x32_bf16(ha, wb, o2, 0, 0, 0);
    }
    if (l15 < 10) {
#pragma unroll
      for (int r = 0; r < 4; ++r) {
        int gr = row0 + wave * 16 + quad * 4 + r;
        out[(size_t)gr * 10 + l15] = a2 * o2[r];
      }
    }
  }
}

extern "C" void kernel_launch(void* const* d_in, const int* in_sizes, int n_in,
                              void* d_out, int out_size, void* d_ws, size_t ws_size,
                              hipStream_t stream) {
  const float* x   = (const float*)d_in[0];
  const int*   w1p = (const int*)d_in[1];
  const int*   m1p = (const int*)d_in[2];
  const float* a1  = (const float*)d_in[3];
  const int*   w2p = (const int*)d_in[4];
  const int*   m2p = (const int*)d_in[5];
  const float* a2  = (const float*)d_in[6];
  unsigned short* w1t = (unsigned short*)d_ws;  // 104*256*8 bf16 = 416 KB scratch
  float* out = (float*)d_out;

  decode_w1_kernel<<<104, 256, 0, stream>>>(w1p, m1p, w1t);
  fused_kernel<<<1024, 512, 0, stream>>>(x, w1t, w2p, m2p, a1, a2, out);
}

// Round 6
// 169.355 us; speedup vs baseline: 1.0179x; 1.0179x over previous
//
#include <hip/hip_runtime.h>
#include <hip/hip_bf16.h>

typedef __bf16 bf16x8 __attribute__((ext_vector_type(8)));
typedef float floatx4 __attribute__((ext_vector_type(4)));

__device__ __forceinline__ unsigned short f2bf(float f) {
  __bf16 b = (__bf16)f;
  return __builtin_bit_cast(unsigned short, b);
}

// ---------------------------------------------------------------------------
// Kernel 1: decode w1 bits -> bf16 {-1,0,+1} in MFMA-FRAGMENT-TRANSPOSED order:
//   w1t[(kq*256 + row)*8 + k]  holds W[row][kq*8 + k],  kq in [0,104)
// (K padded 784 -> 832 with zeros). Fragment rows for one (chunk, quad, wave)
// are 16 consecutive rows = 256 contiguous bytes -> direct-to-VGPR coalesced.
// ---------------------------------------------------------------------------
__global__ void decode_w1_kernel(const int* __restrict__ w1p,
                                 const int* __restrict__ m1p,
                                 unsigned short* __restrict__ w1t) {
  int t = blockIdx.x * 256 + threadIdx.x;   // [0, 104*256)
  int r = t & 255;                          // row 0..255
  int j = t >> 8;                           // byte group (kq) 0..103
  unsigned short vals[8];
#pragma unroll
  for (int k = 0; k < 8; ++k) vals[k] = 0;
  if (j < 98) {
    unsigned int v = (unsigned int)w1p[r * 98 + j];
    unsigned int m = (unsigned int)m1p[r * 98 + j];
#pragma unroll
    for (int k = 0; k < 8; ++k) {           // MSB-first per byte (matches _unpack)
      unsigned int bit = (v >> (7 - k)) & 1u;
      unsigned int mk  = (m >> (7 - k)) & 1u;
      vals[k] = (unsigned short)(mk ? (bit ? 0x3F80u : 0xBF80u) : 0u);  // +1/-1/0
    }
  }
  uint4 pack;
  pack.x = (unsigned)vals[0] | ((unsigned)vals[1] << 16);
  pack.y = (unsigned)vals[2] | ((unsigned)vals[3] << 16);
  pack.z = (unsigned)vals[4] | ((unsigned)vals[5] << 16);
  pack.w = (unsigned)vals[6] | ((unsigned)vals[7] << 16);
  *reinterpret_cast<uint4*>(w1t + t * 8) = pack;
}

// ---------------------------------------------------------------------------
// Kernel 2: fused  h = relu(a1 * x@W1^T);  out = a2 * (h@W2^T)
// v7 = v5 + T14 (issue-early / write-late x staging). One variable changed:
// half-1's x loads are ISSUED before half-0's compute and held in registers
// through the 13-chunk phase (~2us >> HBM latency); cvt+ds_write happen after
// the barrier. Everything else (BM=64, 512thr, W-direct ping-pong from the
// fragment-transposed w1t, epilogue) is v5's proven structure.
//   A-frag: A[m=l15][k=quad*8+j]; B-frag: B^T[n=l15][k=quad*8+j];
//   C/D: col=l15, row=quad*4+reg  (m89-verified layouts).
// ---------------------------------------------------------------------------
#define BM 64
#define HS_LD 264    // 256 + 8 pad: layer-2 Hs reads conflict-free
#define W2_LD 264

// phase-1 LDS (shorts): Xs[52][64][8] = 26624 shorts = 53248 B (one K-half)
// phase-2 overlay:      Hs[64][264] @ 0,  W2s[16][264] @ 16896 (end 21120)
#define OFF_W2 16896

__global__ __launch_bounds__(512, 4) void fused_kernel(
    const float* __restrict__ x,
    const unsigned short* __restrict__ w1t,
    const int* __restrict__ w2p,
    const int* __restrict__ m2p,
    const float* __restrict__ a1p,
    const float* __restrict__ a2p,
    float* __restrict__ out) {
  __shared__ unsigned short smem[26624];   // 53248 B

  const int tid  = threadIdx.x;
  const int wave = tid >> 6;
  const int lane = tid & 63;
  const int l15  = lane & 15;
  const int quad = lane >> 4;
  const int row0 = blockIdx.x * BM;

  floatx4 acc[4][2];
#pragma unroll
  for (int i = 0; i < 4; ++i)
#pragma unroll
    for (int j = 0; j < 2; ++j) acc[i][j] = (floatx4){0.f, 0.f, 0.f, 0.f};

  // W fragment base: B-frag row n = wave*32 + nj*16 + l15 (wave covers 32 cols)
  const unsigned short* wl = w1t + ((size_t)wave * 32 + l15) * 8;

  // x staging coords: r = row 0..63, g0 = base float4-group 0..7
  const int r  = tid >> 3;
  const int g0 = tid & 7;
  const float* xrow = x + (size_t)(row0 + r) * 784;

  bf16x8 bfv[2][2];                         // W ping-pong buffers
  auto pref_w = [&](int cg, int buf) {      // prefetch W frags for global chunk cg
#pragma unroll
    for (int nj = 0; nj < 2; ++nj)
      bfv[buf][nj] = *reinterpret_cast<const bf16x8*>(
          wl + (size_t)(cg * 4 + quad) * 2048 + nj * 128);
  };
  auto mm = [&](int cl, int buf) {          // ds-load A frags for local chunk cl; MFMA
    bf16x8 af[4];
#pragma unroll
    for (int mi = 0; mi < 4; ++mi)
      af[mi] = *reinterpret_cast<const bf16x8*>(
          &smem[((cl * 4 + quad) * 64 + mi * 16 + l15) * 8]);
#pragma unroll
    for (int mi = 0; mi < 4; ++mi)
#pragma unroll
      for (int nj = 0; nj < 2; ++nj)
        acc[mi][nj] = __builtin_amdgcn_mfma_f32_16x16x32_bf16(
            af[mi], bfv[buf][nj], acc[mi][nj], 0, 0, 0);
  };

  // ---- prologue: stage half 0 (cols 0..415, all valid; local group lg=g) ----
  {
    float4 xv[13];
#pragma unroll
    for (int it = 0; it < 13; ++it) {
      int g = g0 + it * 8;                   // 0..103, col = 4g <= 412 < 784
      xv[it] = *reinterpret_cast<const float4*>(xrow + g * 4);
    }
#pragma unroll
    for (int it = 0; it < 13; ++it) {
      int g = g0 + it * 8;
      ushort4 b;
      b.x = f2bf(xv[it].x); b.y = f2bf(xv[it].y);
      b.z = f2bf(xv[it].z); b.w = f2bf(xv[it].w);
      *reinterpret_cast<ushort4*>(&smem[((g >> 1) * 64 + r) * 8 + (g & 1) * 4]) = b;
    }
  }
  __syncthreads();   // half-0 ready

  // ---- T14: issue half-1 batch A x-loads NOW (held through half-0 compute) ----
  float4 xvA[7];
#pragma unroll
  for (int it = 0; it < 7; ++it) {
    int g = 104 + g0 + it * 8;               // <=159, col <=636 < 784: always valid
    xvA[it] = *reinterpret_cast<const float4*>(xrow + g * 4);
  }

  // ---- compute half 0, chunks 0..5 (W ping-pong one ahead) ----
  pref_w(0, 0);
#pragma unroll
  for (int cl = 0; cl < 6; ++cl) {
    pref_w(cl + 1, (cl + 1) & 1);
    mm(cl, cl & 1);
  }

  // batch A has had ~6 chunks of cover: convert to bf16 (frees float regs)
  ushort4 xsA[7];
#pragma unroll
  for (int it = 0; it < 7; ++it) {
    xsA[it].x = f2bf(xvA[it].x); xsA[it].y = f2bf(xvA[it].y);
    xsA[it].z = f2bf(xvA[it].z); xsA[it].w = f2bf(xvA[it].w);
  }
  // issue half-1 batch B loads (tail-guarded: cols >= 784 are zero pad)
  float4 xvB[6];
#pragma unroll
  for (int it = 0; it < 6; ++it) {
    int g = 104 + g0 + (7 + it) * 8;         // up to 207, col up to 828
    if (g * 4 < 784)
      xvB[it] = *reinterpret_cast<const float4*>(xrow + g * 4);
    else
      xvB[it] = (float4){0.f, 0.f, 0.f, 0.f};
  }

  // ---- compute half 0, chunks 6..12 ----
#pragma unroll
  for (int cl = 6; cl < 13; ++cl) {
    if (cl < 12) pref_w(cl + 1, (cl + 1) & 1);
    mm(cl, cl & 1);
  }
  __syncthreads();   // all waves done reading half-0 Xs

  // ---- write half 1 into Xs (loads long since landed; drain is cheap) ----
#pragma unroll
  for (int it = 0; it < 7; ++it) {
    int lg = g0 + it * 8;                    // local group 0..55
    *reinterpret_cast<ushort4*>(&smem[((lg >> 1) * 64 + r) * 8 + (lg & 1) * 4]) = xsA[it];
  }
#pragma unroll
  for (int it = 0; it < 6; ++it) {
    int lg = g0 + (7 + it) * 8;              // local group 56..103
    ushort4 b;
    b.x = f2bf(xvB[it].x); b.y = f2bf(xvB[it].y);
    b.z = f2bf(xvB[it].z); b.w = f2bf(xvB[it].w);
    *reinterpret_cast<ushort4*>(&smem[((lg >> 1) * 64 + r) * 8 + (lg & 1) * 4]) = b;
  }
  __syncthreads();   // half-1 ready

  // ---- compute half 1, chunks 0..12 (global chunks 13..25) ----
  pref_w(13, 0);
#pragma unroll
  for (int cl = 0; cl < 13; ++cl) {
    if (cl < 12) pref_w(13 + cl + 1, (cl + 1) & 1);
    mm(cl, cl & 1);
  }
  __syncthreads();   // done reading Xs before Hs overlay

  // ---- epilogue layer 1: h = relu(a1*acc) -> Hs bf16 (overlays Xs) ----
  const float a1 = a1p[0];
  const float a2 = a2p[0];
#pragma unroll
  for (int mi = 0; mi < 4; ++mi) {
#pragma unroll
    for (int nj = 0; nj < 2; ++nj) {
      int col   = wave * 32 + nj * 16 + l15;
      int rbase = mi * 16 + quad * 4;
#pragma unroll
      for (int rr = 0; rr < 4; ++rr) {
        float h = fmaxf(a1 * acc[mi][nj][rr], 0.f);
        smem[(rbase + rr) * HS_LD + col] = f2bf(h);
      }
    }
  }
  // ---- decode w2 -> W2s[16][264] (rows 10..15 zero) ----
  if (tid < 320) {
    int rr = tid >> 5, j = tid & 31;
    unsigned int v = (unsigned int)w2p[rr * 32 + j];
    unsigned int m = (unsigned int)m2p[rr * 32 + j];
#pragma unroll
    for (int k = 0; k < 8; ++k) {
      unsigned int bit = (v >> (7 - k)) & 1u;
      unsigned int mk  = (m >> (7 - k)) & 1u;
      smem[OFF_W2 + rr * W2_LD + j * 8 + k] =
          (unsigned short)(mk ? (bit ? 0x3F80u : 0xBF80u) : 0u);
    }
  }
  for (int idx = tid; idx < 6 * 256; idx += 512) {
    int rr = 10 + (idx >> 8), c = idx & 255;
    smem[OFF_W2 + rr * W2_LD + c] = 0;
  }
  __syncthreads();

  // ---- layer 2: out[64][10] = Hs @ W2s^T; waves 0..3, 16 rows each, K=256 ----
  if (wave < 4) {
    floatx4 o2 = (floatx4){0.f, 0.f, 0.f, 0.f};
#pragma unroll
    for (int ks = 0; ks < 8; ++ks) {
      bf16x8 ha = *reinterpret_cast<const bf16x8*>(
          &smem[(wave * 16 + l15) * HS_LD + ks * 32 + quad * 8]);
      bf16x8 wb = *reinterpret_cast<const bf16x8*>(
          &smem[OFF_W2 + l15 * W2_LD + ks * 32 + quad * 8]);
      o2 = __builtin_amdgcn_mfma_f32_16x16x32_bf16(ha, wb, o2, 0, 0, 0);
    }
    if (l15 < 10) {
#pragma unroll
      for (int rr = 0; rr < 4; ++rr) {
        int gr = row0 + wave * 16 + quad * 4 + rr;
        out[(size_t)gr * 10 + l15] = a2 * o2[rr];
      }
    }
  }
}

extern "C" void kernel_launch(void* const* d_in, const int* in_sizes, int n_in,
                              void* d_out, int out_size, void* d_ws, size_t ws_size,
                              hipStream_t stream) {
  const float* x   = (const float*)d_in[0];
  const int*   w1p = (const int*)d_in[1];
  const int*   m1p = (const int*)d_in[2];
  const float* a1  = (const float*)d_in[3];
  const int*   w2p = (const int*)d_in[4];
  const int*   m2p = (const int*)d_in[5];
  const float* a2  = (const float*)d_in[6];
  unsigned short* w1t = (unsigned short*)d_ws;  // 104*256*8 bf16 = 416 KB scratch
  float* out = (float*)d_out;

  decode_w1_kernel<<<104, 256, 0, stream>>>(w1p, m1p, w1t);
  fused_kernel<<<512, 512, 0, stream>>>(x, w1t, w2p, m2p, a1, a2, out);
}